// Round 1
// baseline (390.161 us; speedup 1.0000x reference)
//
#include <hip/hip_runtime.h>

#define BATCH 8
#define DIN   512
#define SEQ   8192
#define ECH   1024   // concatenated conv output channels (fore 512 | back 512)
#define HCH   256    // per-direction hidden channels
#define CL    32     // scan chunk length
#define NCHNK (SEQ / CL)   // 256 chunks per row
#define NSC   16           // superchunks (16 chunks each)

typedef __bf16 bf16;
typedef __bf16 bf16x8 __attribute__((ext_vector_type(8)));
typedef float  floatx4 __attribute__((ext_vector_type(4)));

__device__ __forceinline__ void async_ld16(void* lds, const void* g) {
  __builtin_amdgcn_global_load_lds(
      (const __attribute__((address_space(1))) unsigned int*)g,
      (__attribute__((address_space(3))) unsigned int*)lds, 16, 0, 0);
}

__device__ __forceinline__ float bits2f(unsigned u) {
  return __builtin_bit_cast(float, u);
}

// minGRU step: a = sigmoid(-g), bt = sigmoid(g) * (h>=0 ? 1+h : exp(h))
__device__ __forceinline__ void gru_ab(unsigned v, float& a, float& bt) {
  float hh = bits2f(v << 16);
  float g  = bits2f(v & 0xffff0000u);
  float eg = __expf(-g);
  float sg = 1.f / (1.f + eg);   // sigmoid(g)
  a = eg * sg;                    // sigmoid(-g)
  float gv = hh >= 0.f ? 1.f + hh : __expf(hh);
  bt = sg * gv;
}

// ---------------------------------------------------------------------------
// Kernel 1: convert/permute weights to bf16, channel-interleaved (h,gate) pairs.
// ---------------------------------------------------------------------------
__global__ void k_wconv(const float* __restrict__ wf, const float* __restrict__ bfo,
                        const float* __restrict__ wb, const float* __restrict__ bb,
                        bf16* __restrict__ Wb, float* __restrict__ bias) {
  int idx = blockIdx.x * 256 + threadIdx.x;
  if (idx < ECH * DIN) {
    int n = idx >> 9, d = idx & 511;
    int dir = n >> 9, r = n & 511, e = r >> 1, isg = r & 1;
    int s = e + (isg ? HCH : 0);
    const float* w = dir ? wb : wf;
    Wb[idx] = (bf16)w[s * DIN + d];
  }
  if (idx < ECH) {
    int dir = idx >> 9, r = idx & 511, e = r >> 1, isg = r & 1;
    int s = e + (isg ? HCH : 0);
    bias[idx] = (dir ? bb : bfo)[s];
  }
}

// ---------------------------------------------------------------------------
// Kernel 2: tiled transpose + convert  x[b,d,l] fp32 -> xT[b,l,d] bf16
// ---------------------------------------------------------------------------
__global__ void k_xpose(const float* __restrict__ x, bf16* __restrict__ xT) {
  __shared__ float T[64 * 65];
  int t = threadIdx.x;
  int l0 = blockIdx.x * 64;
  int d0 = blockIdx.y * 64;
  int b  = blockIdx.z;
  const float* xb = x + (size_t)b * DIN * SEQ;
#pragma unroll
  for (int p = 0; p < 4; ++p) {
    int dl = (t >> 4) + p * 16;
    int l4 = (t & 15) * 4;
    float4 v = *(const float4*)(xb + (size_t)(d0 + dl) * SEQ + l0 + l4);
    T[dl * 65 + l4 + 0] = v.x;
    T[dl * 65 + l4 + 1] = v.y;
    T[dl * 65 + l4 + 2] = v.z;
    T[dl * 65 + l4 + 3] = v.w;
  }
  __syncthreads();
  bf16* xTb = xT + (size_t)b * SEQ * DIN;
#pragma unroll
  for (int p = 0; p < 2; ++p) {
    int ll = (t >> 3) + p * 32;
    int d8 = (t & 7) * 8;
    bf16x8 h;
#pragma unroll
    for (int j = 0; j < 8; ++j) h[j] = (bf16)T[(d8 + j) * 65 + ll];
    *(bf16x8*)(xTb + (size_t)(l0 + ll) * DIN + d0 + d8) = h;
  }
}

// ---------------------------------------------------------------------------
// Kernel 3: bf16 MFMA GEMM  hg[b,l,n] = sum_d xT[b,l,d] * Wb[n,d] + bias[n]
// 256x256 tile, BK=32, 8 waves (2Mx4N), 16x16x32 frags.
// 4-slot LDS ring staged 3 K-tiles ahead via global_load_lds; counted
// s_waitcnt vmcnt(8) (never drains in steady state); ONE s_barrier per
// K-tile (32 MFMA/barrier). BK=32 row stride (64 B) is naturally
// bank-conflict-free for both the linear staging writes and the l15/quad
// fragment reads, so no XOR swizzle is needed.
// Fused epilogue: bias+pack to Cs[256][268] in LDS, hg store, per-chunk
// minGRU affine composition (A,B) straight from Cs.
// ---------------------------------------------------------------------------
#define BKK 32
#define NKT (DIN / BKK)     // 16 K-tiles
#define CS_STRIDE 268       // 268*2B=536B row stride: pack/store/scan all ~2-way

__launch_bounds__(512, 2)
__global__ void k_gemm(const bf16* __restrict__ xT, const bf16* __restrict__ Wb,
                       const float* __restrict__ bias, bf16* __restrict__ hg,
                       float* __restrict__ Asum, float* __restrict__ Bsum) {
  // 137,216 B: ring4 staging (4 x [A 16KB | B 16KB] = 128 KB)  U  Cs[256][268] bf16
  __shared__ __align__(16) bf16 lds[68608];

  int t = threadIdx.x;
  int lane = t & 63, wave = t >> 6;
  int l15 = lane & 15, quad = lane >> 4;
  int wm = wave >> 2, wn = wave & 3;

  // XCD-locality remap: each XCD gets 4 contiguous l-tiles x all 4 n-tiles.
  int lin = blockIdx.x + 4 * blockIdx.y;      // 0..127 per batch
  int swz = (lin & 7) * 16 + (lin >> 3);      // bijective on 0..127
  int ntile = swz & 3, ltile = swz >> 2;      // 4 n-tiles, 32 l-tiles
  int n0 = ntile * 256;
  int l0 = ltile * 256;
  int b  = blockIdx.z;

  const bf16* gA = xT + ((size_t)b * SEQ + l0) * DIN;
  const bf16* gB = Wb + (size_t)n0 * DIN;

  // staging: per K-tile, 4 loads/thread (A rows 0-127, A rows 128-255, B x2).
  // LDS elem = row*32 + col = t*8  -> wave-uniform base + lane*16B (required).
  int srow = t >> 2;            // 0..127
  int scol = (t & 3) * 8;       // 0,8,16,24

  // bias loads issued before staging: FIFO-retired by the first vmcnt(8).
  float bb4[4];
#pragma unroll
  for (int ni = 0; ni < 4; ++ni) bb4[ni] = bias[n0 + wn * 64 + ni * 16 + l15];

#define STAGE(KT) do {                                                     \
    bf16* dst = lds + ((KT) & 3) * 16384 + t * 8;                          \
    const bf16* sA = gA + (size_t)srow * DIN + (KT) * BKK + scol;          \
    const bf16* sB = gB + (size_t)srow * DIN + (KT) * BKK + scol;          \
    async_ld16(dst,         sA);                                           \
    async_ld16(dst + 4096,  sA + (size_t)128 * DIN);                       \
    async_ld16(dst + 8192,  sB);                                           \
    async_ld16(dst + 12288, sB + (size_t)128 * DIN);                       \
  } while (0)

  STAGE(0); STAGE(1); STAGE(2);

  floatx4 acc[8][4];
#pragma unroll
  for (int i = 0; i < 8; ++i)
#pragma unroll
    for (int j = 0; j < 4; ++j) acc[i][j] = (floatx4){0.f, 0.f, 0.f, 0.f};

#pragma unroll
  for (int kt = 0; kt < NKT; ++kt) {
    // counted wait: K(kt) resident after this wave's wait + the barrier
    // (outstanding = K(kt),K(kt+1),K(kt+2) = 12 -> keep newest 8).
    if (kt <= NKT - 3)      asm volatile("s_waitcnt vmcnt(8)" ::: "memory");
    else if (kt == NKT - 2) asm volatile("s_waitcnt vmcnt(4)" ::: "memory");
    else                    asm volatile("s_waitcnt vmcnt(0)" ::: "memory");
    __builtin_amdgcn_s_barrier();
    asm volatile("" ::: "memory");   // keep LDS reads below the barrier

    // ring slot (kt+3)&3 == (kt-1)&3: all waves finished reading K(kt-1)
    // before the barrier above -> safe to overwrite.
    if (kt + 3 < NKT) STAGE(kt + 3);

    const bf16* As = lds + (kt & 3) * 16384;
    const bf16* Bs = As + 8192;
    bf16x8 af[8], bfr[4];
#pragma unroll
    for (int i = 0; i < 8; ++i)
      af[i] = *(const bf16x8*)(As + (wm * 128 + i * 16 + l15) * BKK + quad * 8);
#pragma unroll
    for (int i = 0; i < 4; ++i)
      bfr[i] = *(const bf16x8*)(Bs + (wn * 64 + i * 16 + l15) * BKK + quad * 8);

    __builtin_amdgcn_s_setprio(1);
#pragma unroll
    for (int mi = 0; mi < 8; ++mi)
#pragma unroll
      for (int ni = 0; ni < 4; ++ni)
        acc[mi][ni] = __builtin_amdgcn_mfma_f32_16x16x32_bf16(
            af[mi], bfr[ni], acc[mi][ni], 0, 0, 0);
    __builtin_amdgcn_s_setprio(0);
  }
#undef STAGE

  __syncthreads();   // all waves done with ring before Cs overwrite

  // epilogue: bias add, pack to bf16 Cs[256][268]
  bf16* Cs = lds;
#pragma unroll
  for (int mi = 0; mi < 8; ++mi)
#pragma unroll
    for (int ni = 0; ni < 4; ++ni)
#pragma unroll
      for (int r = 0; r < 4; ++r) {
        int row = wm * 128 + mi * 16 + quad * 4 + r;
        int col = wn * 64 + ni * 16 + l15;
        Cs[row * CS_STRIDE + col] = (bf16)(acc[mi][ni][r] + bb4[ni]);
      }
  __syncthreads();

  // hg store: 256 rows x 512B, coalesced 16B per lane
  bf16* hgb = hg + ((size_t)b * SEQ + l0) * ECH + n0;
#pragma unroll
  for (int p = 0; p < 16; ++p) {
    int row = p * 16 + (t >> 5);
    int seg = t & 31;
    *(bf16x8*)(hgb + (size_t)row * ECH + seg * 8) =
        *(const bf16x8*)(Cs + row * CS_STRIDE + seg * 8);
  }

  // fused per-chunk minGRU composition: 8 chunks x 128 e-pairs = 2 units/thread
  int dirn = ntile >> 1;               // n0 >> 9
#pragma unroll
  for (int j = 0; j < 2; ++j) {
    int u = t + j * 512;
    int c = u >> 7;                    // chunk within tile (0..7)
    int e = u & 127;                   // e-pair within tile
    float A = 1.f, Bc = 0.f;
#pragma unroll 8
    for (int i = 0; i < CL; ++i) {
      int row = c * CL + (dirn ? (CL - 1 - i) : i);
      unsigned v = *(const unsigned*)(Cs + row * CS_STRIDE + 2 * e);
      float a, bt;
      gru_ab(v, a, bt);
      A *= a;
      Bc = a * Bc + bt;
    }
    int chunkg = ltile * 8 + c;
    int eg = (ntile & 1) * 128 + e;
    size_t o = ((size_t)(b * 2 + dirn) * NCHNK + chunkg) * 256 + eg;
    Asum[o] = A;
    Bsum[o] = Bc;
  }
}

// ---------------------------------------------------------------------------
// Kernel 5a: per-superchunk (16 chunks) composition. 256 blocks x 256 thr.
// ---------------------------------------------------------------------------
__global__ void k_scan2a(const float* __restrict__ Asum, const float* __restrict__ Bsum,
                         float* __restrict__ SA, float* __restrict__ SB) {
  int e = threadIdx.x, sc = blockIdx.x, row2 = blockIdx.y, dir = row2 & 1;
  size_t base = (size_t)row2 * NCHNK;
  float Acc = 1.f, Bcc = 0.f;
#pragma unroll
  for (int i = 0; i < 16; ++i) {
    int c = sc * 16 + (dir ? 15 - i : i);
    size_t o = (base + c) * 256 + e;
    float a = Asum[o], bv = Bsum[o];
    Acc = a * Acc;
    Bcc = a * Bcc + bv;
  }
  size_t so = ((size_t)row2 * NSC + sc) * 256 + e;
  SA[so] = Acc;
  SB[so] = Bcc;
}

// ---------------------------------------------------------------------------
// Kernel 5b: scan the 16 superchunks per row. 16 blocks x 256 thr.
// ---------------------------------------------------------------------------
__global__ void k_scan2b(const float* __restrict__ SA, const float* __restrict__ SB,
                         float* __restrict__ hsc) {
  int e = threadIdx.x, row2 = blockIdx.x, dir = row2 & 1;
  float h = 0.f;
  for (int i = 0; i < NSC; ++i) {
    int sc = dir ? NSC - 1 - i : i;
    size_t o = ((size_t)row2 * NSC + sc) * 256 + e;
    hsc[o] = h;
    h = SA[o] * h + SB[o];
  }
}

// ---------------------------------------------------------------------------
// Kernel 5c: distribute carries to every chunk. 256 blocks x 256 thr.
// ---------------------------------------------------------------------------
__global__ void k_scan2c(const float* __restrict__ Asum, const float* __restrict__ Bsum,
                         const float* __restrict__ hsc, float* __restrict__ hin) {
  int e = threadIdx.x, sc = blockIdx.x, row2 = blockIdx.y, dir = row2 & 1;
  float h = hsc[((size_t)row2 * NSC + sc) * 256 + e];
#pragma unroll
  for (int i = 0; i < 16; ++i) {
    int c = sc * 16 + (dir ? 15 - i : i);
    size_t o = ((size_t)row2 * NCHNK + c) * 256 + e;
    hin[o] = h;
    h = Asum[o] * h + Bsum[o];
  }
}

// ---------------------------------------------------------------------------
// Kernel 6: recompute local scan with carry-in, transpose via LDS (stride 33),
// write out[b, dir*256+e, l] as coalesced float4.
// ---------------------------------------------------------------------------
__global__ void k_scan3(const bf16* __restrict__ hg, const float* __restrict__ hin,
                        float* __restrict__ out) {
  __shared__ float T[256 * 33];
  int t = threadIdx.x;
  int chunk = blockIdx.x, dir = blockIdx.y, b = blockIdx.z;
  const bf16* hb = hg + (size_t)b * SEQ * ECH + dir * 512 + 2 * t;
  float h = hin[((size_t)(b * 2 + dir) * NCHNK + chunk) * 256 + t];
  int lbase = chunk * CL;
#pragma unroll 8
  for (int i = 0; i < CL; ++i) {
    int ll = dir ? (CL - 1 - i) : i;
    unsigned v = *(const unsigned*)(hb + (size_t)(lbase + ll) * ECH);
    float a, bt;
    gru_ab(v, a, bt);
    h = a * h + bt;
    T[t * 33 + ll] = h;
  }
  __syncthreads();
  float* ob = out + ((size_t)b * 512 + dir * 256) * SEQ + lbase;
#pragma unroll
  for (int p = 0; p < 8; ++p) {
    int row = p * 32 + (t >> 3);   // e channel
    int c4 = (t & 7) * 4;          // l within chunk
    float4 v4;
    v4.x = T[row * 33 + c4 + 0];
    v4.y = T[row * 33 + c4 + 1];
    v4.z = T[row * 33 + c4 + 2];
    v4.w = T[row * 33 + c4 + 3];
    *(float4*)(ob + (size_t)row * SEQ + c4) = v4;
  }
}

// ---------------------------------------------------------------------------
extern "C" void kernel_launch(void* const* d_in, const int* in_sizes, int n_in,
                              void* d_out, int out_size, void* d_ws, size_t ws_size,
                              hipStream_t stream) {
  const float* x   = (const float*)d_in[0];
  const float* wf  = (const float*)d_in[1];
  const float* bfo = (const float*)d_in[2];
  const float* wb  = (const float*)d_in[3];
  const float* bb  = (const float*)d_in[4];
  float* out = (float*)d_out;
  char* ws = (char*)d_ws;

  // workspace layout (bytes):
  bf16*  xT   = (bf16*)(ws);                       // 67,108,864
  bf16*  hg   = (bf16*)(ws + 67108864);            // 134,217,728
  bf16*  Wbm  = (bf16*)(ws + 201326592);           // 1,048,576
  float* bias = (float*)(ws + 202375168);          // 4,096
  float* Asum = (float*)(ws + 202379264);          // 4,194,304
  float* Bsum = (float*)(ws + 206573568);          // 4,194,304
  float* hin  = (float*)(ws + 210767872);          // 4,194,304
  float* SA   = (float*)(ws + 214962176);          // 262,144
  float* SB   = (float*)(ws + 215224320);          // 262,144
  float* hsc  = (float*)(ws + 215486464);          // 262,144  (total ~215.7 MB)

  k_wconv<<<2048, 256, 0, stream>>>(wf, bfo, wb, bb, Wbm, bias);
  k_xpose<<<dim3(SEQ / 64, DIN / 64, BATCH), 256, 0, stream>>>(x, xT);
  k_gemm<<<dim3(ECH / 256, SEQ / 256, BATCH), 512, 0, stream>>>(xT, Wbm, bias, hg,
                                                                Asum, Bsum);
  k_scan2a<<<dim3(NSC, 16), 256, 0, stream>>>(Asum, Bsum, SA, SB);
  k_scan2b<<<16, 256, 0, stream>>>(SA, SB, hsc);
  k_scan2c<<<dim3(NSC, 16), 256, 0, stream>>>(Asum, Bsum, hsc, hin);
  k_scan3<<<dim3(NCHNK, 2, BATCH), 256, 0, stream>>>(hg, hin, out);
}

// Round 2
// 389.982 us; speedup vs baseline: 1.0005x; 1.0005x over previous
//
#include <hip/hip_runtime.h>

#define BATCH 8
#define DIN   512
#define SEQ   8192
#define ECH   1024   // concatenated conv output channels (fore 512 | back 512)
#define HCH   256    // per-direction hidden channels
#define CL    32     // scan chunk length
#define NCHNK (SEQ / CL)   // 256 chunks per row
#define NSC   16           // superchunks (16 chunks each)

typedef __bf16 bf16;
typedef __bf16 bf16x8 __attribute__((ext_vector_type(8)));
typedef float  floatx4 __attribute__((ext_vector_type(4)));

__device__ __forceinline__ void async_ld16(void* lds, const void* g) {
  __builtin_amdgcn_global_load_lds(
      (const __attribute__((address_space(1))) unsigned int*)g,
      (__attribute__((address_space(3))) unsigned int*)lds, 16, 0, 0);
}

__device__ __forceinline__ float bits2f(unsigned u) {
  return __builtin_bit_cast(float, u);
}

// minGRU step: a = sigmoid(-g), bt = sigmoid(g) * (h>=0 ? 1+h : exp(h))
__device__ __forceinline__ void gru_ab(unsigned v, float& a, float& bt) {
  float hh = bits2f(v << 16);
  float g  = bits2f(v & 0xffff0000u);
  float eg = __expf(-g);
  float sg = 1.f / (1.f + eg);   // sigmoid(g)
  a = eg * sg;                    // sigmoid(-g)
  float gv = hh >= 0.f ? 1.f + hh : __expf(hh);
  bt = sg * gv;
}

// ---------------------------------------------------------------------------
// Kernel 1: convert/permute weights to bf16, channel-interleaved (h,gate) pairs.
// ---------------------------------------------------------------------------
__global__ void k_wconv(const float* __restrict__ wf, const float* __restrict__ bfo,
                        const float* __restrict__ wb, const float* __restrict__ bb,
                        bf16* __restrict__ Wb, float* __restrict__ bias) {
  int idx = blockIdx.x * 256 + threadIdx.x;
  if (idx < ECH * DIN) {
    int n = idx >> 9, d = idx & 511;
    int dir = n >> 9, r = n & 511, e = r >> 1, isg = r & 1;
    int s = e + (isg ? HCH : 0);
    const float* w = dir ? wb : wf;
    Wb[idx] = (bf16)w[s * DIN + d];
  }
  if (idx < ECH) {
    int dir = idx >> 9, r = idx & 511, e = r >> 1, isg = r & 1;
    int s = e + (isg ? HCH : 0);
    bias[idx] = (dir ? bb : bfo)[s];
  }
}

// ---------------------------------------------------------------------------
// Kernel 2: tiled transpose + convert  x[b,d,l] fp32 -> xT[b,l,d] bf16
// ---------------------------------------------------------------------------
__global__ void k_xpose(const float* __restrict__ x, bf16* __restrict__ xT) {
  __shared__ float T[64 * 65];
  int t = threadIdx.x;
  int l0 = blockIdx.x * 64;
  int d0 = blockIdx.y * 64;
  int b  = blockIdx.z;
  const float* xb = x + (size_t)b * DIN * SEQ;
#pragma unroll
  for (int p = 0; p < 4; ++p) {
    int dl = (t >> 4) + p * 16;
    int l4 = (t & 15) * 4;
    float4 v = *(const float4*)(xb + (size_t)(d0 + dl) * SEQ + l0 + l4);
    T[dl * 65 + l4 + 0] = v.x;
    T[dl * 65 + l4 + 1] = v.y;
    T[dl * 65 + l4 + 2] = v.z;
    T[dl * 65 + l4 + 3] = v.w;
  }
  __syncthreads();
  bf16* xTb = xT + (size_t)b * SEQ * DIN;
#pragma unroll
  for (int p = 0; p < 2; ++p) {
    int ll = (t >> 3) + p * 32;
    int d8 = (t & 7) * 8;
    bf16x8 h;
#pragma unroll
    for (int j = 0; j < 8; ++j) h[j] = (bf16)T[(d8 + j) * 65 + ll];
    *(bf16x8*)(xTb + (size_t)(l0 + ll) * DIN + d0 + d8) = h;
  }
}

// ---------------------------------------------------------------------------
// Kernel 3: bf16 MFMA GEMM  hg[b,l,n] = sum_d xT[b,l,d] * Wb[n,d] + bias[n]
// 256x256 tile, BK=64, 8 waves (2Mx4N), 16x16x32 frags.
// m201-style 4-phase/K-tile schedule: per phase {ds_read subtile || stage one
// 128x64 half-tile -> s_barrier -> lgkmcnt(0) -> setprio(1)+16 MFMA -> barrier}.
// Counted s_waitcnt vmcnt(6) ONCE per K-tile (3 half-tiles stay in flight).
// XOR-swizzled [128][64] half-tiles (pre-swizzled global source, linear LDS
// dest for global_load_lds; same XOR on the ds_read side) - measured 0
// bank conflicts at this geometry in the 128-tile version.
// Stage slots chosen so every overwrite happens strictly after the barrier
// bounding the last read of that region:
//   quadrant order (Gray): p0 (afLo,b01), p1 (afLo,b23), p2 (afHi,b23),
//   p3 (afHi,b01).  Stages: p0 -> next-tile Bh1 (non-compute buffer),
//   p2 -> tile+2 Bh0, p3 -> tile+2 Ah0+Ah1 (compute buffer, regions dead).
// Fused epilogue: bias+pack to Cs[256][268] in LDS, hg store, per-chunk
// minGRU affine composition (A,B) straight from Cs.
// ---------------------------------------------------------------------------
#define BKK 64
#define NKT (DIN / BKK)     // 8 K-tiles
#define CS_STRIDE 268       // 268*2B=536B row stride for epilogue tile

__launch_bounds__(512, 2)
__global__ void k_gemm(const bf16* __restrict__ xT, const bf16* __restrict__ Wb,
                       const float* __restrict__ bias, bf16* __restrict__ hg,
                       float* __restrict__ Asum, float* __restrict__ Bsum) {
  // 137,216 B: dbuf staging (2 x [Ah0|Ah1|Bh0|Bh1] x 16 KB = 128 KB) U Cs[256][268]
  __shared__ __align__(16) bf16 lds[68608];

  int t = threadIdx.x;
  int lane = t & 63, wave = t >> 6;
  int l15 = lane & 15, quad = lane >> 4, swr = l15 & 7;
  int wm = wave >> 2, wn = wave & 3;

  // XCD-locality remap: each XCD gets 4 contiguous l-tiles x all 4 n-tiles.
  int lin = blockIdx.x + 4 * blockIdx.y;      // 0..127 per batch
  int swz = (lin & 7) * 16 + (lin >> 3);      // bijective on 0..127
  int ntile = swz & 3, ltile = swz >> 2;      // 4 n-tiles, 32 l-tiles
  int n0 = ntile * 256;
  int l0 = ltile * 256;
  int b  = blockIdx.z;

  const bf16* gA = xT + ((size_t)b * SEQ + l0) * DIN;
  const bf16* gB = Wb + (size_t)n0 * DIN;

  // bias loads issued first: retired by the first counted vmcnt (FIFO).
  float bb4[4];
#pragma unroll
  for (int ni = 0; ni < 4; ++ni) bb4[ni] = bias[n0 + wn * 64 + ni * 16 + l15];

  // stage one 128x64 half-tile: linear LDS dest (wave-uniform base + lane*16B),
  // XOR-preswizzled global source column. 2 global_load_lds per thread.
#define STAGE_HALF(DST, GSRC, K0) do {                                        \
    _Pragma("unroll")                                                         \
    for (int j = 0; j < 2; ++j) {                                             \
      int i_ = t + j * 512;                                                   \
      int row_ = i_ >> 3, c8_ = i_ & 7;                                       \
      async_ld16((DST) + i_ * 8,                                              \
                 (GSRC) + (size_t)row_ * DIN + (K0) + ((c8_ ^ (row_ & 7)) * 8)); \
    }                                                                         \
  } while (0)

  // prologue: tile0 all 4 halves, tile1 {Bh0, Ah0, Ah1}  (14 loads/thread... 14 total)
  STAGE_HALF(lds +     0, gA, 0);
  STAGE_HALF(lds +  8192, gA + (size_t)128 * DIN, 0);
  STAGE_HALF(lds + 16384, gB, 0);
  STAGE_HALF(lds + 24576, gB + (size_t)128 * DIN, 0);
  STAGE_HALF(lds + 32768 + 16384, gB, BKK);
  STAGE_HALF(lds + 32768 +     0, gA, BKK);
  STAGE_HALF(lds + 32768 +  8192, gA + (size_t)128 * DIN, BKK);

  floatx4 acc[8][4];
#pragma unroll
  for (int i = 0; i < 8; ++i)
#pragma unroll
    for (int j = 0; j < 4; ++j) acc[i][j] = (floatx4){0.f, 0.f, 0.f, 0.f};

  asm volatile("s_waitcnt vmcnt(6)" ::: "memory");   // tile0 resident, 3 halves in flight
  __builtin_amdgcn_s_barrier();
  asm volatile("" ::: "memory");

#pragma unroll
  for (int kt = 0; kt < NKT; ++kt) {
    const bf16* Ab = lds + (kt & 1) * 32768 + wm * 8192;
    const bf16* Bb = lds + (kt & 1) * 32768 + 16384 + (wn >> 1) * 8192;
    bf16* curb = lds + (kt & 1) * 32768;
    bf16* nxtb = lds + ((kt & 1) ^ 1) * 32768;
    int bro = (wn & 1) * 64 + l15;

    bf16x8 af[4][2], b01[2][2], b23[2][2];

    // ---------------- P0: read afLo(8) + b01(4); stage t(kt+1).Bh1 ----------
#pragma unroll
    for (int mi = 0; mi < 4; ++mi)
#pragma unroll
      for (int k2 = 0; k2 < 2; ++k2)
        af[mi][k2] = *(const bf16x8*)(Ab + (mi * 16 + l15) * 64 +
                                      (((k2 * 4 + quad) ^ swr) * 8));
#pragma unroll
    for (int ni = 0; ni < 2; ++ni)
#pragma unroll
      for (int k2 = 0; k2 < 2; ++k2)
        b01[ni][k2] = *(const bf16x8*)(Bb + (bro + ni * 16) * 64 +
                                       (((k2 * 4 + quad) ^ swr) * 8));
    if (kt + 1 < NKT)
      STAGE_HALF(nxtb + 24576, gB + (size_t)128 * DIN, (kt + 1) * BKK);
    __builtin_amdgcn_s_barrier();
    asm volatile("s_waitcnt lgkmcnt(0)" ::: "memory");
    __builtin_amdgcn_s_setprio(1);
#pragma unroll
    for (int mi = 0; mi < 4; ++mi)
#pragma unroll
      for (int ni = 0; ni < 2; ++ni)
#pragma unroll
        for (int k2 = 0; k2 < 2; ++k2)
          acc[mi][ni] = __builtin_amdgcn_mfma_f32_16x16x32_bf16(
              af[mi][k2], b01[ni][k2], acc[mi][ni], 0, 0, 0);
    __builtin_amdgcn_s_setprio(0);
    __builtin_amdgcn_s_barrier();
    asm volatile("" ::: "memory");

    // ---------------- P1: read b23(4) ---------------------------------------
#pragma unroll
    for (int ni = 0; ni < 2; ++ni)
#pragma unroll
      for (int k2 = 0; k2 < 2; ++k2)
        b23[ni][k2] = *(const bf16x8*)(Bb + (bro + 32 + ni * 16) * 64 +
                                       (((k2 * 4 + quad) ^ swr) * 8));
    __builtin_amdgcn_s_barrier();
    asm volatile("s_waitcnt lgkmcnt(0)" ::: "memory");
    __builtin_amdgcn_s_setprio(1);
#pragma unroll
    for (int mi = 0; mi < 4; ++mi)
#pragma unroll
      for (int ni = 0; ni < 2; ++ni)
#pragma unroll
        for (int k2 = 0; k2 < 2; ++k2)
          acc[mi][2 + ni] = __builtin_amdgcn_mfma_f32_16x16x32_bf16(
              af[mi][k2], b23[ni][k2], acc[mi][2 + ni], 0, 0, 0);
    __builtin_amdgcn_s_setprio(0);
    __builtin_amdgcn_s_barrier();
    asm volatile("" ::: "memory");

    // ---------------- P2: read afHi(8); stage t(kt+2).Bh0 -------------------
    // (b01/b23 reads of this buffer all completed before the p1 end barrier)
#pragma unroll
    for (int mi = 0; mi < 4; ++mi)
#pragma unroll
      for (int k2 = 0; k2 < 2; ++k2)
        af[mi][k2] = *(const bf16x8*)(Ab + (64 + mi * 16 + l15) * 64 +
                                      (((k2 * 4 + quad) ^ swr) * 8));
    if (kt + 2 < NKT)
      STAGE_HALF(curb + 16384, gB, (kt + 2) * BKK);
    __builtin_amdgcn_s_barrier();
    asm volatile("s_waitcnt lgkmcnt(0)" ::: "memory");
    __builtin_amdgcn_s_setprio(1);
#pragma unroll
    for (int mi = 0; mi < 4; ++mi)
#pragma unroll
      for (int ni = 0; ni < 2; ++ni)
#pragma unroll
        for (int k2 = 0; k2 < 2; ++k2)
          acc[4 + mi][2 + ni] = __builtin_amdgcn_mfma_f32_16x16x32_bf16(
              af[mi][k2], b23[ni][k2], acc[4 + mi][2 + ni], 0, 0, 0);
    __builtin_amdgcn_s_setprio(0);
    __builtin_amdgcn_s_barrier();
    asm volatile("" ::: "memory");

    // ---------------- P3: stage t(kt+2).Ah0+Ah1; MFMA from regs -------------
    // (afLo reads completed before p0 end barrier, afHi before p2 end barrier)
    if (kt + 2 < NKT) {
      STAGE_HALF(curb, gA, (kt + 2) * BKK);
      STAGE_HALF(curb + 8192, gA + (size_t)128 * DIN, (kt + 2) * BKK);
    }
    __builtin_amdgcn_s_barrier();
    __builtin_amdgcn_s_setprio(1);
#pragma unroll
    for (int mi = 0; mi < 4; ++mi)
#pragma unroll
      for (int ni = 0; ni < 2; ++ni)
#pragma unroll
        for (int k2 = 0; k2 < 2; ++k2)
          acc[4 + mi][ni] = __builtin_amdgcn_mfma_f32_16x16x32_bf16(
              af[mi][k2], b01[ni][k2], acc[4 + mi][ni], 0, 0, 0);
    __builtin_amdgcn_s_setprio(0);
    // counted wait once per K-tile: next tile fully resident, 3 halves in flight
    if (kt <= NKT - 3)      asm volatile("s_waitcnt vmcnt(6)" ::: "memory");
    else if (kt == NKT - 2) asm volatile("s_waitcnt vmcnt(0)" ::: "memory");
    __builtin_amdgcn_s_barrier();
    asm volatile("" ::: "memory");
  }
#undef STAGE_HALF

  __syncthreads();   // full drain before Cs overlays the staging buffers

  // epilogue: bias add, pack to bf16 Cs[256][268]
  bf16* Cs = lds;
#pragma unroll
  for (int mi = 0; mi < 8; ++mi)
#pragma unroll
    for (int ni = 0; ni < 4; ++ni)
#pragma unroll
      for (int r = 0; r < 4; ++r) {
        int row = wm * 128 + mi * 16 + quad * 4 + r;
        int col = wn * 64 + ni * 16 + l15;
        Cs[row * CS_STRIDE + col] = (bf16)(acc[mi][ni][r] + bb4[ni]);
      }
  __syncthreads();

  // hg store: 256 rows x 512B, coalesced 16B per lane
  bf16* hgb = hg + ((size_t)b * SEQ + l0) * ECH + n0;
#pragma unroll
  for (int p = 0; p < 16; ++p) {
    int row = p * 16 + (t >> 5);
    int seg = t & 31;
    *(bf16x8*)(hgb + (size_t)row * ECH + seg * 8) =
        *(const bf16x8*)(Cs + row * CS_STRIDE + seg * 8);
  }

  // fused per-chunk minGRU composition: 8 chunks x 128 e-pairs = 2 units/thread
  int dirn = ntile >> 1;               // n0 >> 9
#pragma unroll
  for (int j = 0; j < 2; ++j) {
    int u = t + j * 512;
    int c = u >> 7;                    // chunk within tile (0..7)
    int e = u & 127;                   // e-pair within tile
    float A = 1.f, Bc = 0.f;
#pragma unroll 8
    for (int i = 0; i < CL; ++i) {
      int row = c * CL + (dirn ? (CL - 1 - i) : i);
      unsigned v = *(const unsigned*)(Cs + row * CS_STRIDE + 2 * e);
      float a, bt;
      gru_ab(v, a, bt);
      A *= a;
      Bc = a * Bc + bt;
    }
    int chunkg = ltile * 8 + c;
    int eg = (ntile & 1) * 128 + e;
    size_t o = ((size_t)(b * 2 + dirn) * NCHNK + chunkg) * 256 + eg;
    Asum[o] = A;
    Bsum[o] = Bc;
  }
}

// ---------------------------------------------------------------------------
// Kernel 5a: per-superchunk (16 chunks) composition. 256 blocks x 256 thr.
// ---------------------------------------------------------------------------
__global__ void k_scan2a(const float* __restrict__ Asum, const float* __restrict__ Bsum,
                         float* __restrict__ SA, float* __restrict__ SB) {
  int e = threadIdx.x, sc = blockIdx.x, row2 = blockIdx.y, dir = row2 & 1;
  size_t base = (size_t)row2 * NCHNK;
  float Acc = 1.f, Bcc = 0.f;
#pragma unroll
  for (int i = 0; i < 16; ++i) {
    int c = sc * 16 + (dir ? 15 - i : i);
    size_t o = (base + c) * 256 + e;
    float a = Asum[o], bv = Bsum[o];
    Acc = a * Acc;
    Bcc = a * Bcc + bv;
  }
  size_t so = ((size_t)row2 * NSC + sc) * 256 + e;
  SA[so] = Acc;
  SB[so] = Bcc;
}

// ---------------------------------------------------------------------------
// Kernel 5b: scan the 16 superchunks per row. 16 blocks x 256 thr.
// ---------------------------------------------------------------------------
__global__ void k_scan2b(const float* __restrict__ SA, const float* __restrict__ SB,
                         float* __restrict__ hsc) {
  int e = threadIdx.x, row2 = blockIdx.x, dir = row2 & 1;
  float h = 0.f;
  for (int i = 0; i < NSC; ++i) {
    int sc = dir ? NSC - 1 - i : i;
    size_t o = ((size_t)row2 * NSC + sc) * 256 + e;
    hsc[o] = h;
    h = SA[o] * h + SB[o];
  }
}

// ---------------------------------------------------------------------------
// Kernel 5c: distribute carries to every chunk. 256 blocks x 256 thr.
// ---------------------------------------------------------------------------
__global__ void k_scan2c(const float* __restrict__ Asum, const float* __restrict__ Bsum,
                         const float* __restrict__ hsc, float* __restrict__ hin) {
  int e = threadIdx.x, sc = blockIdx.x, row2 = blockIdx.y, dir = row2 & 1;
  float h = hsc[((size_t)row2 * NSC + sc) * 256 + e];
#pragma unroll
  for (int i = 0; i < 16; ++i) {
    int c = sc * 16 + (dir ? 15 - i : i);
    size_t o = ((size_t)row2 * NCHNK + c) * 256 + e;
    hin[o] = h;
    h = Asum[o] * h + Bsum[o];
  }
}

// ---------------------------------------------------------------------------
// Kernel 6: recompute local scan with carry-in, transpose via LDS (stride 33),
// write out[b, dir*256+e, l] as coalesced float4.
// ---------------------------------------------------------------------------
__global__ void k_scan3(const bf16* __restrict__ hg, const float* __restrict__ hin,
                        float* __restrict__ out) {
  __shared__ float T[256 * 33];
  int t = threadIdx.x;
  int chunk = blockIdx.x, dir = blockIdx.y, b = blockIdx.z;
  const bf16* hb = hg + (size_t)b * SEQ * ECH + dir * 512 + 2 * t;
  float h = hin[((size_t)(b * 2 + dir) * NCHNK + chunk) * 256 + t];
  int lbase = chunk * CL;
#pragma unroll 8
  for (int i = 0; i < CL; ++i) {
    int ll = dir ? (CL - 1 - i) : i;
    unsigned v = *(const unsigned*)(hb + (size_t)(lbase + ll) * ECH);
    float a, bt;
    gru_ab(v, a, bt);
    h = a * h + bt;
    T[t * 33 + ll] = h;
  }
  __syncthreads();
  float* ob = out + ((size_t)b * 512 + dir * 256) * SEQ + lbase;
#pragma unroll
  for (int p = 0; p < 8; ++p) {
    int row = p * 32 + (t >> 3);   // e channel
    int c4 = (t & 7) * 4;          // l within chunk
    float4 v4;
    v4.x = T[row * 33 + c4 + 0];
    v4.y = T[row * 33 + c4 + 1];
    v4.z = T[row * 33 + c4 + 2];
    v4.w = T[row * 33 + c4 + 3];
    *(float4*)(ob + (size_t)row * SEQ + c4) = v4;
  }
}

// ---------------------------------------------------------------------------
extern "C" void kernel_launch(void* const* d_in, const int* in_sizes, int n_in,
                              void* d_out, int out_size, void* d_ws, size_t ws_size,
                              hipStream_t stream) {
  const float* x   = (const float*)d_in[0];
  const float* wf  = (const float*)d_in[1];
  const float* bfo = (const float*)d_in[2];
  const float* wb  = (const float*)d_in[3];
  const float* bb  = (const float*)d_in[4];
  float* out = (float*)d_out;
  char* ws = (char*)d_ws;

  // workspace layout (bytes):
  bf16*  xT   = (bf16*)(ws);                       // 67,108,864
  bf16*  hg   = (bf16*)(ws + 67108864);            // 134,217,728
  bf16*  Wbm  = (bf16*)(ws + 201326592);           // 1,048,576
  float* bias = (float*)(ws + 202375168);          // 4,096
  float* Asum = (float*)(ws + 202379264);          // 4,194,304
  float* Bsum = (float*)(ws + 206573568);          // 4,194,304
  float* hin  = (float*)(ws + 210767872);          // 4,194,304
  float* SA   = (float*)(ws + 214962176);          // 262,144
  float* SB   = (float*)(ws + 215224320);          // 262,144
  float* hsc  = (float*)(ws + 215486464);          // 262,144  (total ~215.7 MB)

  k_wconv<<<2048, 256, 0, stream>>>(wf, bfo, wb, bb, Wbm, bias);
  k_xpose<<<dim3(SEQ / 64, DIN / 64, BATCH), 256, 0, stream>>>(x, xT);
  k_gemm<<<dim3(ECH / 256, SEQ / 256, BATCH), 512, 0, stream>>>(xT, Wbm, bias, hg,
                                                                Asum, Bsum);
  k_scan2a<<<dim3(NSC, 16), 256, 0, stream>>>(Asum, Bsum, SA, SB);
  k_scan2b<<<16, 256, 0, stream>>>(SA, SB, hsc);
  k_scan2c<<<dim3(NSC, 16), 256, 0, stream>>>(Asum, Bsum, hsc, hin);
  k_scan3<<<dim3(NCHNK, 2, BATCH), 256, 0, stream>>>(hg, hin, out);
}